// Round 3
// baseline (115.255 us; speedup 1.0000x reference)
//
#include <hip/hip_runtime.h>
#include <hip/hip_bf16.h>

// Correlation loss via bf16 MFMA, exploiting pair-matrix symmetry.
// dm - dh = s[p] + s[q] - 2*(g_m - g_h),  s = sum(pm^2) - sum(ph^2).
// g accumulated as: MFMA(-he, +he) then MFMA(msi, msi) on the same acc.
// d(p,q) is symmetric -> compute only upper-triangle 16x16 tiles (136 of 256):
// total = diag + 2 * offdiag. Tiles interleaved mod 4 across the 4 waves.

#define WS   16
#define PSZ  256
#define IMG  512
#define IMG2 (IMG * IMG)
#define XSTR 40          // ushorts per xs row = 80 B: 16B-aligned, bank-rotating

typedef __attribute__((ext_vector_type(8))) short short8;
typedef __attribute__((ext_vector_type(4))) float float4v;

static __device__ __forceinline__ unsigned short f2bf(float v) {
    union { __hip_bfloat16 b; unsigned short u; } cv;
    cv.b = __float2bfloat16(v);
    return cv.u;
}
static __device__ __forceinline__ float bf2f(unsigned short u) {
    union { unsigned int u; float f; } cv;
    cv.u = ((unsigned int)u) << 16;
    return cv.f;
}

__global__ __launch_bounds__(256, 4)
void corr_loss_kernel(const float* __restrict__ msi,
                      const float* __restrict__ he,
                      const int* __restrict__ i_idx,
                      const int* __restrict__ j_idx,
                      float* __restrict__ out,
                      float scale)
{
    __shared__ __align__(16) unsigned short xs[PSZ * XSTR];   // msi bf16 [p][k]
    __shared__ __align__(16) unsigned short heA[PSZ * 8];     // -he  [p][k0..7]
    __shared__ __align__(16) unsigned short heB[PSZ * 8];     // +he
    __shared__ __align__(16) unsigned int   zq[4];            // zero frag
    __shared__ __align__(16) float s_lds[PSZ];
    __shared__ __align__(16) float m_lds[PSZ];
    __shared__ float red[4];

    const int b = blockIdx.x;
    const int t = threadIdx.x;
    const int i0 = i_idx[b], j0 = j_idx[b];

    // ---- stage column p = t: bf16-round msi, +/-he, s and mask ----
    {
        const int r = t >> 4, c = t & 15;
        const float* mp = msi + (size_t)(i0 + r) * IMG + (j0 + c);
        float sm = 0.f;
#pragma unroll
        for (int g = 0; g < 4; ++g) {
            float v[8];
#pragma unroll
            for (int k = 0; k < 8; ++k) v[k] = mp[(size_t)(g * 8 + k) * IMG2];
            unsigned int pk[4];
#pragma unroll
            for (int k = 0; k < 4; ++k) {
                unsigned short lo = f2bf(v[2 * k]), hi = f2bf(v[2 * k + 1]);
                float fl = bf2f(lo), fh = bf2f(hi);
                sm = fmaf(fl, fl, sm);
                sm = fmaf(fh, fh, sm);
                pk[k] = (unsigned int)lo | ((unsigned int)hi << 16);
            }
            *(uint4*)&xs[t * XSTR + g * 8] = make_uint4(pk[0], pk[1], pk[2], pk[3]);
        }
        const float* hp = he + (size_t)(i0 + r) * IMG + (j0 + c);
        float hsum = 0.f, sh = 0.f;
        unsigned short hb[3];
#pragma unroll
        for (int ch = 0; ch < 3; ++ch) {
            float hv = hp[(size_t)ch * IMG2];
            hsum += hv;                       // mask from exact fp32 (matches ref)
            hb[ch] = f2bf(hv);
            float hr = bf2f(hb[ch]);
            sh = fmaf(hr, hr, sh);            // s_h from rounded (consistent w/ gram)
        }
        *(uint4*)&heB[t * 8] =
            make_uint4((unsigned)hb[0] | ((unsigned)hb[1] << 16), (unsigned)hb[2], 0u, 0u);
        unsigned short n0 = hb[0] ^ 0x8000u, n1 = hb[1] ^ 0x8000u, n2 = hb[2] ^ 0x8000u;
        *(uint4*)&heA[t * 8] =
            make_uint4((unsigned)n0 | ((unsigned)n1 << 16), (unsigned)n2, 0u, 0u);
        s_lds[t] = sm - sh;
        m_lds[t] = (hsum >= 0.05f) ? 1.f : 0.f;
        if (t < 4) zq[t] = 0u;
    }
    __syncthreads();

    const int lane = t & 63, w = t >> 6;
    const int m = lane & 15, quad = lane >> 4;
    const short8 zfrag = *(const short8*)zq;

    float accD = 0.f, accO = 0.f;

    int l = 0;   // linear upper-tri tile index at start of row ti
    for (int ti = 0; ti < 16; ++ti) {
        const int cnt = 16 - ti;
        const int r = (w - l) & 3;           // first offset in this row for wave w
        if (r < cnt) {
            const int ri = ti << 4;
            short8  Am  = *(const short8*)&xs[(ri + m) * XSTR + (quad << 3)];
            short8  Ah  = (quad == 0) ? *(const short8*)&heA[(ri + m) << 3] : zfrag;
            float4v sr4 = *(const float4v*)&s_lds[ri + (quad << 2)];
            float4v mr4 = *(const float4v*)&m_lds[ri + (quad << 2)];

            auto tile = [&](int tj) -> float {
                const int cj = tj << 4;
                short8 Bm = *(const short8*)&xs[(cj + m) * XSTR + (quad << 3)];
                short8 Bh = (quad == 0) ? *(const short8*)&heB[(cj + m) << 3] : zfrag;
                float  sc = s_lds[cj + m];
                float  mc = m_lds[cj + m];
                float4v g = {0.f, 0.f, 0.f, 0.f};
                g = __builtin_amdgcn_mfma_f32_16x16x32_bf16(Ah, Bh, g, 0, 0, 0); // -g_h
                g = __builtin_amdgcn_mfma_f32_16x16x32_bf16(Am, Bm, g, 0, 0, 0); // +g_m
                float lacc = 0.f;
#pragma unroll
                for (int reg = 0; reg < 4; ++reg) {
                    float tt = sr4[reg] + sc;
                    float rr = fmaf(-2.f, g[reg], tt);
                    lacc = fmaf(mr4[reg] * mc, fabsf(rr), lacc);
                }
                return lacc;
            };

            int tj = ti + r;
            if (r == 0) { accD += tile(ti); tj += 4; }   // diagonal tile, weight 1
            for (; tj < 16; tj += 4) accO += tile(tj);   // off-diag, weight 2
        }
        l += cnt;
    }

    float acc = fmaf(2.f, accO, accD);

    // block reduction -> one atomic per block
#pragma unroll
    for (int off = 32; off > 0; off >>= 1)
        acc += __shfl_down(acc, off, 64);
    if (lane == 0) red[w] = acc;
    __syncthreads();
    if (t == 0)
        atomicAdd(out, (red[0] + red[1] + red[2] + red[3]) * scale);
}

extern "C" void kernel_launch(void* const* d_in, const int* in_sizes, int n_in,
                              void* d_out, int out_size, void* d_ws, size_t ws_size,
                              hipStream_t stream) {
    const float* msi   = (const float*)d_in[0];
    const float* he    = (const float*)d_in[1];
    const int*   i_idx = (const int*)d_in[2];
    const int*   j_idx = (const int*)d_in[3];
    const int    NB    = in_sizes[2];
    float*       out   = (float*)d_out;

    hipMemsetAsync(out, 0, sizeof(float) * out_size, stream);

    const float scale = 1.0f / ((float)(PSZ * PSZ) * (float)(NB / 5));
    corr_loss_kernel<<<NB, 256, 0, stream>>>(msi, he, i_idx, j_idx, out, scale);
}

// Round 4
// 111.826 us; speedup vs baseline: 1.0307x; 1.0307x over previous
//
#include <hip/hip_runtime.h>
#include <hip/hip_bf16.h>

// Correlation loss, fully folded into bf16 MFMA.
// m_p m_q (dm - dh) = m_p m_q (s_p + s_q - 2 g_m + 2 g_h) emerges directly from
// two chained 16x16x32 MFMAs per tile:
//   MFMA1: A = -2*m*msi~ (K=32), B = m*msi~          -> -2 m m g_m
//   MFMA2: A = m*{2h~0,2h~1,2h~2,s_hi,s_lo,1,1,0},
//          B = m*{h~0,h~1,h~2,1,1,s_hi,s_lo,0}       -> m m (2 g_h + s_p + s_q)
// with s = (sum msi~^2 - sum he~^2) split into bf16 hi+lo words.
// Epilogue per tile: acc += |g[reg]| (abs is a free VOP modifier).
// Layout-agnostic: we sum |.| over every accumulator element.
// One block/patch, 4 waves x (4 row-tiles x 16 col-tiles), B shared across the
// 4 row-tiles (4 independent MFMA chains for latency hiding).

#define PSZ  256
#define IMG  512
#define IMG2 (IMG * IMG)
#define XSTR 40          // ushorts per xs row = 80 B: 16B-aligned, bank-rotating

typedef __attribute__((ext_vector_type(8))) short short8;
typedef __attribute__((ext_vector_type(4))) float float4v;

static __device__ __forceinline__ unsigned short f2bf(float v) {
    union { __hip_bfloat16 b; unsigned short u; } cv;
    cv.b = __float2bfloat16(v);
    return cv.u;
}
static __device__ __forceinline__ float bf2f(unsigned short u) {
    union { unsigned int u; float f; } cv;
    cv.u = ((unsigned int)u) << 16;
    return cv.f;
}

__global__ __launch_bounds__(256, 4)
void corr_loss_kernel(const float* __restrict__ msi,
                      const float* __restrict__ he,
                      const int* __restrict__ i_idx,
                      const int* __restrict__ j_idx,
                      float* __restrict__ out,
                      float scale)
{
    __shared__ __align__(16) unsigned short xs[PSZ * XSTR];  // m*bf16(msi) [p][k]
    __shared__ __align__(16) unsigned short eA[PSZ * 8];     // extras A-frag / column
    __shared__ __align__(16) unsigned short eB[PSZ * 8];     // extras B-frag / column
    __shared__ float red[4];

    const int b = blockIdx.x;
    const int t = threadIdx.x;
    const int i0 = i_idx[b], j0 = j_idx[b];

    // ---- stage column p = t ----
    {
        const int r = t >> 4, c = t & 15;
        const float* hp = he + (size_t)(i0 + r) * IMG + (j0 + c);
        const float h0 = hp[0], h1 = hp[IMG2], h2 = hp[2 * IMG2];
        const float mf = (h0 + h1 + h2 >= 0.05f) ? 1.f : 0.f;   // mask: exact fp32
        const unsigned short hb0 = f2bf(h0 * mf), hb1 = f2bf(h1 * mf), hb2 = f2bf(h2 * mf);
        const float hr0 = bf2f(hb0), hr1 = bf2f(hb1), hr2 = bf2f(hb2);
        const float sh = hr0 * hr0 + hr1 * hr1 + hr2 * hr2;

        const float* mp = msi + (size_t)(i0 + r) * IMG + (j0 + c);
        float sm = 0.f;
#pragma unroll
        for (int g = 0; g < 4; ++g) {
            unsigned int pk[4];
#pragma unroll
            for (int k = 0; k < 4; ++k) {
                float v0 = mp[(size_t)(g * 8 + 2 * k)     * IMG2] * mf;
                float v1 = mp[(size_t)(g * 8 + 2 * k + 1) * IMG2] * mf;
                unsigned short lo = f2bf(v0), hi = f2bf(v1);
                float fl = bf2f(lo), fh = bf2f(hi);
                sm = fmaf(fl, fl, sm);
                sm = fmaf(fh, fh, sm);
                pk[k] = (unsigned int)lo | ((unsigned int)hi << 16);
            }
            *(uint4*)&xs[t * XSTR + g * 8] = make_uint4(pk[0], pk[1], pk[2], pk[3]);
        }
        const float s = sm - sh;                 // masked already (m^2 = m)
        const unsigned short shi = f2bf(s);
        const unsigned short slo = f2bf(s - bf2f(shi));
        const unsigned short mb  = (mf != 0.f) ? (unsigned short)0x3F80 : (unsigned short)0;
        const unsigned short d0  = f2bf(2.f * hr0);   // exact: exponent+1
        const unsigned short d1  = f2bf(2.f * hr1);
        const unsigned short d2  = f2bf(2.f * hr2);
        // eA = {2h0, 2h1, 2h2, s_hi, s_lo, m, m, 0}
        *(uint4*)&eA[t * 8] = make_uint4(
            (unsigned)d0 | ((unsigned)d1 << 16),
            (unsigned)d2 | ((unsigned)shi << 16),
            (unsigned)slo | ((unsigned)mb << 16),
            (unsigned)mb);
        // eB = {h0, h1, h2, m, m, s_hi, s_lo, 0}
        *(uint4*)&eB[t * 8] = make_uint4(
            (unsigned)hb0 | ((unsigned)hb1 << 16),
            (unsigned)hb2 | ((unsigned)mb << 16),
            (unsigned)mb | ((unsigned)shi << 16),
            (unsigned)slo);
    }
    __syncthreads();

    const int lane = t & 63, w = t >> 6;
    const int mrow = lane & 15, quad = lane >> 4;
    const short8 zfrag = {0, 0, 0, 0, 0, 0, 0, 0};

    // hoist A-frags for this wave's 4 row-tiles; on-the-fly x~ -> -2*x~
    // (packed bf16: sign flip + exponent+1; no carry since |x|<2, x>=0)
    short8 Am[4], Ah[4];
#pragma unroll
    for (int ii = 0; ii < 4; ++ii) {
        const int ri = ((w << 2) + ii) * 16 + mrow;
        uint4 u = *(const uint4*)&xs[ri * XSTR + (quad << 3)];
        u.x = (u.x ^ 0x80008000u) + 0x00800080u;
        u.y = (u.y ^ 0x80008000u) + 0x00800080u;
        u.z = (u.z ^ 0x80008000u) + 0x00800080u;
        u.w = (u.w ^ 0x80008000u) + 0x00800080u;
        Am[ii] = *(const short8*)&u;
        Ah[ii] = (quad == 0) ? *(const short8*)&eA[ri << 3] : zfrag;
    }

    float acc[4] = {0.f, 0.f, 0.f, 0.f};
#pragma unroll 4
    for (int j = 0; j < 16; ++j) {
        const int cj = (j << 4) + mrow;
        short8 Bm = *(const short8*)&xs[cj * XSTR + (quad << 3)];
        short8 Bh = (quad == 0) ? *(const short8*)&eB[cj << 3] : zfrag;
        float4v g[4];
#pragma unroll
        for (int ii = 0; ii < 4; ++ii) {
            g[ii] = (float4v){0.f, 0.f, 0.f, 0.f};
            g[ii] = __builtin_amdgcn_mfma_f32_16x16x32_bf16(Ah[ii], Bh, g[ii], 0, 0, 0);
            g[ii] = __builtin_amdgcn_mfma_f32_16x16x32_bf16(Am[ii], Bm, g[ii], 0, 0, 0);
        }
#pragma unroll
        for (int ii = 0; ii < 4; ++ii) {
            acc[ii] += fabsf(g[ii][0]);
            acc[ii] += fabsf(g[ii][1]);
            acc[ii] += fabsf(g[ii][2]);
            acc[ii] += fabsf(g[ii][3]);
        }
    }
    float a = (acc[0] + acc[1]) + (acc[2] + acc[3]);

    // block reduction -> one atomic per block
#pragma unroll
    for (int off = 32; off > 0; off >>= 1)
        a += __shfl_down(a, off, 64);
    if (lane == 0) red[w] = a;
    __syncthreads();
    if (t == 0)
        atomicAdd(out, (red[0] + red[1] + red[2] + red[3]) * scale);
}

extern "C" void kernel_launch(void* const* d_in, const int* in_sizes, int n_in,
                              void* d_out, int out_size, void* d_ws, size_t ws_size,
                              hipStream_t stream) {
    const float* msi   = (const float*)d_in[0];
    const float* he    = (const float*)d_in[1];
    const int*   i_idx = (const int*)d_in[2];
    const int*   j_idx = (const int*)d_in[3];
    const int    NB    = in_sizes[2];
    float*       out   = (float*)d_out;

    hipMemsetAsync(out, 0, sizeof(float) * out_size, stream);

    const float scale = 1.0f / ((float)(PSZ * PSZ) * (float)(NB / 5));
    corr_loss_kernel<<<NB, 256, 0, stream>>>(msi, he, i_idx, j_idx, out, scale);
}

// Round 5
// 108.706 us; speedup vs baseline: 1.0602x; 1.0287x over previous
//
#include <hip/hip_runtime.h>
#include <hip/hip_bf16.h>

// Correlation loss, fully folded into bf16 MFMA.
// m_p m_q (dm - dh) = m_p m_q (s_p + s_q - 2 g_m + 2 g_h) from two chained
// 16x16x32 MFMAs per tile (see r4). Epilogue: acc += |g[reg]|.
// r5: no global atomics (per-block partial -> d_ws, tiny reduce kernel),
// staging prefetches all 35 global loads into registers before converting.

#define PSZ  256
#define IMG  512
#define IMG2 (IMG * IMG)
#define XSTR 40          // ushorts per xs row = 80 B (16B-aligned; b128 2-way max)

typedef __attribute__((ext_vector_type(8))) short short8;
typedef __attribute__((ext_vector_type(4))) float float4v;

static __device__ __forceinline__ unsigned short f2bf(float v) {
    union { __hip_bfloat16 b; unsigned short u; } cv;
    cv.b = __float2bfloat16(v);
    return cv.u;
}
static __device__ __forceinline__ float bf2f(unsigned short u) {
    union { unsigned int u; float f; } cv;
    cv.u = ((unsigned int)u) << 16;
    return cv.f;
}

__global__ __launch_bounds__(256, 4)
void corr_loss_kernel(const float* __restrict__ msi,
                      const float* __restrict__ he,
                      const int* __restrict__ i_idx,
                      const int* __restrict__ j_idx,
                      float* __restrict__ partial)
{
    __shared__ __align__(16) unsigned short xs[PSZ * XSTR];  // m*bf16(msi) [p][k]
    __shared__ __align__(16) unsigned short eA[PSZ * 8];     // extras A-frag / column
    __shared__ __align__(16) unsigned short eB[PSZ * 8];     // extras B-frag / column
    __shared__ float red[4];

    const int b = blockIdx.x;
    const int t = threadIdx.x;
    const int i0 = i_idx[b], j0 = j_idx[b];

    // ---- stage column p = t: prefetch ALL loads, then convert ----
    {
        const int r = t >> 4, c = t & 15;
        const float* hp = he + (size_t)(i0 + r) * IMG + (j0 + c);
        const float* mp = msi + (size_t)(i0 + r) * IMG + (j0 + c);

        float h0 = hp[0], h1 = hp[IMG2], h2 = hp[2 * IMG2];
        float v[32];
#pragma unroll
        for (int ch = 0; ch < 32; ++ch) v[ch] = mp[(size_t)ch * IMG2];

        const float mf = (h0 + h1 + h2 >= 0.05f) ? 1.f : 0.f;   // mask: exact fp32
        const unsigned short hb0 = f2bf(h0 * mf), hb1 = f2bf(h1 * mf), hb2 = f2bf(h2 * mf);
        const float hr0 = bf2f(hb0), hr1 = bf2f(hb1), hr2 = bf2f(hb2);
        const float sh = hr0 * hr0 + hr1 * hr1 + hr2 * hr2;

        float sm = 0.f;
#pragma unroll
        for (int g = 0; g < 4; ++g) {
            unsigned int pk[4];
#pragma unroll
            for (int k = 0; k < 4; ++k) {
                unsigned short lo = f2bf(v[g * 8 + 2 * k]     * mf);
                unsigned short hi = f2bf(v[g * 8 + 2 * k + 1] * mf);
                float fl = bf2f(lo), fh = bf2f(hi);
                sm = fmaf(fl, fl, sm);
                sm = fmaf(fh, fh, sm);
                pk[k] = (unsigned int)lo | ((unsigned int)hi << 16);
            }
            *(uint4*)&xs[t * XSTR + g * 8] = make_uint4(pk[0], pk[1], pk[2], pk[3]);
        }
        const float s = sm - sh;                 // masked already (m^2 = m)
        const unsigned short shi = f2bf(s);
        const unsigned short slo = f2bf(s - bf2f(shi));
        const unsigned short mb  = (mf != 0.f) ? (unsigned short)0x3F80 : (unsigned short)0;
        const unsigned short d0  = f2bf(2.f * hr0);   // exact: exponent+1
        const unsigned short d1  = f2bf(2.f * hr1);
        const unsigned short d2  = f2bf(2.f * hr2);
        // eA = {2h0, 2h1, 2h2, s_hi, s_lo, m, m, 0}
        *(uint4*)&eA[t * 8] = make_uint4(
            (unsigned)d0 | ((unsigned)d1 << 16),
            (unsigned)d2 | ((unsigned)shi << 16),
            (unsigned)slo | ((unsigned)mb << 16),
            (unsigned)mb);
        // eB = {h0, h1, h2, m, m, s_hi, s_lo, 0}
        *(uint4*)&eB[t * 8] = make_uint4(
            (unsigned)hb0 | ((unsigned)hb1 << 16),
            (unsigned)hb2 | ((unsigned)mb << 16),
            (unsigned)mb | ((unsigned)shi << 16),
            (unsigned)slo);
    }
    __syncthreads();

    const int lane = t & 63, w = t >> 6;
    const int mrow = lane & 15, quad = lane >> 4;
    const short8 zfrag = {0, 0, 0, 0, 0, 0, 0, 0};

    // hoist A-frags for this wave's 4 row-tiles; on-the-fly x~ -> -2*x~
    // (packed bf16: sign flip + exponent+1; no carry since 0 <= x < 2)
    short8 Am[4], Ah[4];
#pragma unroll
    for (int ii = 0; ii < 4; ++ii) {
        const int ri = ((w << 2) + ii) * 16 + mrow;
        uint4 u = *(const uint4*)&xs[ri * XSTR + (quad << 3)];
        u.x = (u.x ^ 0x80008000u) + 0x00800080u;
        u.y = (u.y ^ 0x80008000u) + 0x00800080u;
        u.z = (u.z ^ 0x80008000u) + 0x00800080u;
        u.w = (u.w ^ 0x80008000u) + 0x00800080u;
        Am[ii] = *(const short8*)&u;
        Ah[ii] = (quad == 0) ? *(const short8*)&eA[ri << 3] : zfrag;
    }

    float acc[4] = {0.f, 0.f, 0.f, 0.f};
#pragma unroll 4
    for (int j = 0; j < 16; ++j) {
        const int cj = (j << 4) + mrow;
        short8 Bm = *(const short8*)&xs[cj * XSTR + (quad << 3)];
        short8 Bh = (quad == 0) ? *(const short8*)&eB[cj << 3] : zfrag;
        float4v g[4];
#pragma unroll
        for (int ii = 0; ii < 4; ++ii) {
            g[ii] = (float4v){0.f, 0.f, 0.f, 0.f};
            g[ii] = __builtin_amdgcn_mfma_f32_16x16x32_bf16(Ah[ii], Bh, g[ii], 0, 0, 0);
            g[ii] = __builtin_amdgcn_mfma_f32_16x16x32_bf16(Am[ii], Bm, g[ii], 0, 0, 0);
        }
#pragma unroll
        for (int ii = 0; ii < 4; ++ii) {
            acc[ii] += fabsf(g[ii][0]);
            acc[ii] += fabsf(g[ii][1]);
            acc[ii] += fabsf(g[ii][2]);
            acc[ii] += fabsf(g[ii][3]);
        }
    }
    float a = (acc[0] + acc[1]) + (acc[2] + acc[3]);

    // block reduction -> ONE plain store per block (no global atomics)
#pragma unroll
    for (int off = 32; off > 0; off >>= 1)
        a += __shfl_down(a, off, 64);
    if (lane == 0) red[w] = a;
    __syncthreads();
    if (t == 0)
        partial[b] = (red[0] + red[1]) + (red[2] + red[3]);
}

__global__ __launch_bounds__(256)
void reduce_kernel(const float* __restrict__ partial, float* __restrict__ out,
                   int n, float scale)
{
    __shared__ float red[4];
    float a = 0.f;
    for (int i = threadIdx.x; i < n; i += 256) a += partial[i];
#pragma unroll
    for (int off = 32; off > 0; off >>= 1)
        a += __shfl_down(a, off, 64);
    const int lane = threadIdx.x & 63, w = threadIdx.x >> 6;
    if (lane == 0) red[w] = a;
    __syncthreads();
    if (threadIdx.x == 0)
        out[0] = ((red[0] + red[1]) + (red[2] + red[3])) * scale;
}

extern "C" void kernel_launch(void* const* d_in, const int* in_sizes, int n_in,
                              void* d_out, int out_size, void* d_ws, size_t ws_size,
                              hipStream_t stream) {
    const float* msi   = (const float*)d_in[0];
    const float* he    = (const float*)d_in[1];
    const int*   i_idx = (const int*)d_in[2];
    const int*   j_idx = (const int*)d_in[3];
    const int    NB    = in_sizes[2];
    float*       out   = (float*)d_out;
    float*       part  = (float*)d_ws;        // NB floats of scratch

    const float scale = 1.0f / ((float)(PSZ * PSZ) * (float)(NB / 5));
    corr_loss_kernel<<<NB, 256, 0, stream>>>(msi, he, i_idx, j_idx, part);
    reduce_kernel<<<1, 256, 0, stream>>>(part, out, NB, scale);
}